// Round 8
// baseline (392.888 us; speedup 1.0000x reference)
//
#include <hip/hip_runtime.h>
#include <hip/hip_cooperative_groups.h>
#include <math.h>

namespace cg = cooperative_groups;

// Static graph dims
#define BATCH   16384
#define IN_DIM  512
#define NH      128
#define NO      256
#define L2E     1.4426950408889634f

__device__ __forceinline__ float fast_rcp(float x) { return __builtin_amdgcn_rcpf(x); }
__device__ __forceinline__ float fast_exp2(float x) {
#if __has_builtin(__builtin_amdgcn_exp2f)
    return __builtin_amdgcn_exp2f(x);
#else
    return exp2f(x);
#endif
}
__device__ __forceinline__ int rfl(int v) { return __builtin_amdgcn_readfirstlane(v); }

__device__ __forceinline__ float fast_tanh(float z) {
    float ex = fast_exp2(2.f * L2E * z);
    return 1.f - 2.f * fast_rcp(1.f + ex);
}
__device__ __forceinline__ float fast_sig(float z) {
    float ex = fast_exp2(-L2E * z);
    return fast_rcp(1.f + ex);
}
__device__ __forceinline__ float act_k(int a) {
    return (a == 2) ? (2.f * L2E) : ((a == 4) ? -L2E : 0.f);
}

// act ids: 1=identity, 2=tanh, 3=relu, 4=sigmoid. `a` wave-uniform -> scalar branch;
// identity/relu skip the quarter-rate exp2/rcp entirely.
__device__ __forceinline__ void acc_act4(float4& acc, float4 v, float w, int a) {
    float zx = v.x * w, zy = v.y * w, zz = v.z * w, zw = v.w * w;
    if (a == 2) {
        acc.x += fast_tanh(zx); acc.y += fast_tanh(zy);
        acc.z += fast_tanh(zz); acc.w += fast_tanh(zw);
    } else if (a == 4) {
        acc.x += fast_sig(zx); acc.y += fast_sig(zy);
        acc.z += fast_sig(zz); acc.w += fast_sig(zw);
    } else if (a == 3) {
        acc.x += fmaxf(zx, 0.f); acc.y += fmaxf(zy, 0.f);
        acc.z += fmaxf(zz, 0.f); acc.w += fmaxf(zw, 0.f);
    } else {
        acc.x += zx; acc.y += zy; acc.z += zz; acc.w += zw;
    }
}

__device__ __forceinline__ unsigned int f2bf_rne(float f) {
    unsigned int u = __float_as_uint(f);
    return (u + 0x7FFFu + ((u >> 16) & 1u)) >> 16;
}
__device__ __forceinline__ float bf_lo(unsigned int u) { return __uint_as_float(u << 16); }
__device__ __forceinline__ float bf_hi(unsigned int u) { return __uint_as_float(u & 0xFFFF0000u); }

__device__ __forceinline__ int lower_bound_dev(const int* __restrict__ arr, int n, int v) {
    int lo = 0, hi = n;
    while (lo < hi) { int m = (lo + hi) >> 1; if (arr[m] < v) lo = m + 1; else hi = m; }
    return lo;
}

// ---- shared inner loops (used by coop kernel AND standalone fallbacks) ----
__device__ __forceinline__ float4 run_hidden_row(const unsigned short* __restrict__ xt,
                                                 const int4* __restrict__ packed_h,
                                                 int e0, int e1, int bi) {
    float4 acc = make_float4(0.f, 0.f, 0.f, 0.f);
    #pragma unroll 4
    for (int e = e0; e < e1; ++e) {
        int4 p  = packed_h[e];                       // uniform addr -> s_load
        int col = rfl(p.x);
        int a   = rfl(p.y);
        float w = __int_as_float(rfl(p.z));
        uint2 uu = *(const uint2*)(xt + (size_t)col * BATCH + bi);
        float4 v = make_float4(bf_lo(uu.x), bf_hi(uu.x), bf_lo(uu.y), bf_hi(uu.y));
        acc_act4(acc, v, w, a);
    }
    return acc;
}
__device__ __forceinline__ float4 run_output_row(const unsigned short* __restrict__ xt,
                                                 const float* __restrict__ Ht,
                                                 const int4* __restrict__ packed_o,
                                                 int e0, int e1, int bi) {
    float4 acc = make_float4(0.f, 0.f, 0.f, 0.f);
    #pragma unroll 4
    for (int e = e0; e < e1; ++e) {
        int4 p  = packed_o[e];
        int col = rfl(p.x);
        int a   = rfl(p.y);
        float w = __int_as_float(rfl(p.z));
        float4 v;
        if (col < IN_DIM) {                           // wave-uniform branch
            uint2 uu = *(const uint2*)(xt + (size_t)col * BATCH + bi);
            v = make_float4(bf_lo(uu.x), bf_hi(uu.x), bf_lo(uu.y), bf_hi(uu.y));
        } else {
            v = *(const float4*)&Ht[(size_t)(col - IN_DIM) * BATCH + bi];
        }
        acc_act4(acc, v, w, a);
    }
    return acc;
}

// XCD-coherent slice decode (1024-block grids): s in 0..63
__device__ __forceinline__ void decode_slice(int bid, int& s, int& rg) {
    int xcd = bid & 7;
    int m   = bid >> 3;
    rg      = m & 15;
    int u   = m >> 4;
    s = ((u >> 1) << 4) | (xcd << 1) | (u & 1);
}

// =============== single cooperative kernel: transpose+pack | hidden | output ===============
// 1024 blocks x 512 thr, 33KB LDS, VGPR<=64 -> exactly 4 blocks/CU co-resident.
#define OBS 260
__global__ __launch_bounds__(512, 8)
void wann_coop(const float* __restrict__ x,
               const int* __restrict__ rows_h, const int* __restrict__ cols_h,
               const int* __restrict__ acts_h, const float* __restrict__ wh,
               const int* __restrict__ rows_o, const int* __restrict__ cols_o,
               const int* __restrict__ acts_o, const float* __restrict__ wo,
               float* __restrict__ out, int Eh, int Eo,
               unsigned short* __restrict__ xt, float* __restrict__ Ht,
               int* __restrict__ offs_h, int* __restrict__ offs_o,
               int4* __restrict__ packed_h, int4* __restrict__ packed_o)
{
    __shared__ float smem[64 * 129];     // 33 KB: transpose tile, reused as OB[16][260]
    cg::grid_group grid = cg::this_grid();
    const int tid  = threadIdx.x;
    const int lane = tid & 63;
    const int wv   = tid >> 6;
    const int bid  = blockIdx.x;

    // ---------- phase A: x -> bf16 xt (64-batch x 128-col tiles) + CSR/pack ----------
    {
        const int bt = bid >> 2, ct = bid & 3;
        const int b0 = bt * 64, c0 = ct * 128;
        #pragma unroll
        for (int it = 0; it < 4; ++it) {
            int r = (tid >> 5) + it * 16;
            int i = tid & 31;
            float4 f = *(const float4*)&x[(size_t)(b0 + r) * IN_DIM + c0 + i * 4];
            float* d = &smem[r * 129 + i * 4];
            d[0] = f.x; d[1] = f.y; d[2] = f.z; d[3] = f.w;   // b128, conflict-free
        }
        __syncthreads();
        {
            int col  = tid >> 2;          // 0..127
            int part = tid & 3;           // 16 batches each
            unsigned int u[8];
            #pragma unroll
            for (int j = 0; j < 8; ++j) {
                float lo = smem[(part * 16 + 2 * j)     * 129 + col];
                float hi = smem[(part * 16 + 2 * j + 1) * 129 + col];
                u[j] = f2bf_rne(lo) | (f2bf_rne(hi) << 16);
            }
            size_t base = (size_t)(c0 + col) * BATCH + b0 + part * 16;   // ushort idx
            *(uint4*)&xt[base]     = make_uint4(u[0], u[1], u[2], u[3]);
            *(uint4*)&xt[base + 8] = make_uint4(u[4], u[5], u[6], u[7]);
        }
        // CSR offsets + packed edges on low global ids
        int g = bid * 512 + tid;
        if (g <= NH) offs_h[g] = lower_bound_dev(rows_h, Eh, g);
        else if (g <= NH + 1 + NO) offs_o[g - (NH + 1)] = lower_bound_dev(rows_o, Eo, g - (NH + 1));
        int u2 = g - (NH + 1 + NO + 1);
        if (u2 >= 0 && u2 < Eh) {
            int a = acts_h[u2];
            packed_h[u2] = make_int4(cols_h[u2], a, __float_as_int(wh[u2]), 0);
        }
        u2 -= Eh;
        if (u2 >= 0 && u2 < Eo) {
            int a = acts_o[u2];
            packed_o[u2] = make_int4(cols_o[u2], a, __float_as_int(wo[u2]), 0);
        }
    }
    grid.sync();

    // ---------- phase B: hidden — wave = 1 row x 256-batch (4/lane) ----------
    {
        int s, rg;
        decode_slice(bid, s, rg);
        const int bi = s * 256 + lane * 4;
        const int r  = rg * 8 + wv;
        const int e0 = rfl(offs_h[r]);
        const int e1 = rfl(offs_h[r + 1]);
        float4 acc = run_hidden_row(xt, packed_h, e0, e1, bi);
        *(float4*)&Ht[(size_t)r * BATCH + bi] = acc;
    }
    grid.sync();

    // ---------- phase C: output — wave = 2 rows x 256-batch (4/lane) ----------
    {
        float* OB = smem;                 // [16][OBS] = 16.6 KB of the 33 KB
        int s, rg;
        decode_slice(bid, s, rg);
        const int rb = s * 256;
        const int r0 = rg * 16;
        const int bi = rb + lane * 4;
        #pragma unroll
        for (int rr = wv * 2; rr < wv * 2 + 2; ++rr) {
            const int r  = r0 + rr;
            const int e0 = rfl(offs_o[r]);
            const int e1 = rfl(offs_o[r + 1]);
            float4 acc = run_output_row(xt, Ht, packed_o, e0, e1, bi);
            OB[rr * OBS + lane * 4 + 0] = fast_tanh(acc.x);
            OB[rr * OBS + lane * 4 + 1] = fast_tanh(acc.y);
            OB[rr * OBS + lane * 4 + 2] = fast_tanh(acc.z);
            OB[rr * OBS + lane * 4 + 3] = fast_tanh(acc.w);
        }
        __syncthreads();
        // out[rb+b][r0 + c4*4 ..]: 4 lanes cover one b's 64B chunk; OB reads <=2-way
        #pragma unroll
        for (int it = 0; it < 2; ++it) {
            int v  = tid + it * 512;
            int c4 = v & 3;
            int b  = v >> 2;
            float4 o;
            o.x = OB[(c4 * 4 + 0) * OBS + b];
            o.y = OB[(c4 * 4 + 1) * OBS + b];
            o.z = OB[(c4 * 4 + 2) * OBS + b];
            o.w = OB[(c4 * 4 + 3) * OBS + b];
            *(float4*)&out[(size_t)(rb + b) * NO + r0 + c4 * 4] = o;
        }
    }
}

// =============== fallback tier 1: proven 3-kernel path (R6 config) ===============
__global__ __launch_bounds__(256)
void prep_fused(const float* __restrict__ x, unsigned short* __restrict__ xt,
                const int* __restrict__ rows_h, const int* __restrict__ cols_h,
                const int* __restrict__ acts_h, const float* __restrict__ wh,
                const int* __restrict__ rows_o, const int* __restrict__ cols_o,
                const int* __restrict__ acts_o, const float* __restrict__ wo,
                int Eh, int Eo, int tile_blocks,
                int* __restrict__ offs_h, int* __restrict__ offs_o,
                int4* __restrict__ packed_h, int4* __restrict__ packed_o) {
    __shared__ float tile[64 * 65];
    if ((int)blockIdx.x < tile_blocks) {
        const int b0 = (blockIdx.x & (BATCH / 64 - 1)) * 64;
        const int c0 = (blockIdx.x / (BATCH / 64)) * 64;
        #pragma unroll
        for (int it = 0; it < 4; ++it) {
            int v = threadIdx.x + it * 256;
            int r = v >> 4, i = v & 15;
            const float4* row = (const float4*)(x + (size_t)(b0 + r) * IN_DIM + c0);
            float4 f = row[i];
            tile[r * 65 + i * 4 + 0] = f.x;
            tile[r * 65 + i * 4 + 1] = f.y;
            tile[r * 65 + i * 4 + 2] = f.z;
            tile[r * 65 + i * 4 + 3] = f.w;
        }
        __syncthreads();
        #pragma unroll
        for (int it = 0; it < 8; ++it) {
            int v = threadIdx.x + it * 256;
            int c = v >> 5, p = v & 31;
            int b = p * 2;
            unsigned int u = f2bf_rne(tile[b * 65 + c]) | (f2bf_rne(tile[(b + 1) * 65 + c]) << 16);
            *(unsigned int*)&xt[(size_t)(c0 + c) * BATCH + b0 + b] = u;
        }
        return;
    }
    int t = (blockIdx.x - tile_blocks) * 256 + threadIdx.x;
    if (t <= NH) offs_h[t] = lower_bound_dev(rows_h, Eh, t);
    else if (t <= NH + 1 + NO) offs_o[t - (NH + 1)] = lower_bound_dev(rows_o, Eo, t - (NH + 1));
    int u = t - (NH + 1 + NO + 1);
    if (u >= 0 && u < Eh) {
        int a = acts_h[u];
        packed_h[u] = make_int4(cols_h[u], a, __float_as_int(wh[u]), 0);
    }
    u -= Eh;
    if (u >= 0 && u < Eo) {
        int a = acts_o[u];
        packed_o[u] = make_int4(cols_o[u], a, __float_as_int(wo[u]), 0);
    }
}

__global__ __launch_bounds__(512)
void hidden_kernel(const unsigned short* __restrict__ xt, const int* __restrict__ offs_h,
                   const int4* __restrict__ packed_h, float* __restrict__ Ht) {
    const int lane = threadIdx.x & 63;
    const int wv   = threadIdx.x >> 6;
    int s, rg;
    decode_slice(blockIdx.x, s, rg);
    const int bi = s * 256 + lane * 4;
    const int r  = rg * 8 + wv;
    const int e0 = rfl(offs_h[r]);
    const int e1 = rfl(offs_h[r + 1]);
    float4 acc = run_hidden_row(xt, packed_h, e0, e1, bi);
    *(float4*)&Ht[(size_t)r * BATCH + bi] = acc;
}

__global__ __launch_bounds__(512)
void output_kernel(const unsigned short* __restrict__ xt, const float* __restrict__ Ht,
                   const int* __restrict__ offs_o, const int4* __restrict__ packed_o,
                   float* __restrict__ out) {
    __shared__ float OB[16 * OBS];
    const int lane = threadIdx.x & 63;
    const int wv   = threadIdx.x >> 6;
    int s, rg;
    decode_slice(blockIdx.x, s, rg);
    const int rb = s * 256;
    const int r0 = rg * 16;
    const int bi = rb + lane * 4;
    #pragma unroll
    for (int rr = wv * 2; rr < wv * 2 + 2; ++rr) {
        const int r  = r0 + rr;
        const int e0 = rfl(offs_o[r]);
        const int e1 = rfl(offs_o[r + 1]);
        float4 acc = run_output_row(xt, Ht, packed_o, e0, e1, bi);
        OB[rr * OBS + lane * 4 + 0] = fast_tanh(acc.x);
        OB[rr * OBS + lane * 4 + 1] = fast_tanh(acc.y);
        OB[rr * OBS + lane * 4 + 2] = fast_tanh(acc.z);
        OB[rr * OBS + lane * 4 + 3] = fast_tanh(acc.w);
    }
    __syncthreads();
    #pragma unroll
    for (int it = 0; it < 2; ++it) {
        int v  = threadIdx.x + it * 512;
        int c4 = v & 3;
        int b  = v >> 2;
        float4 o;
        o.x = OB[(c4 * 4 + 0) * OBS + b];
        o.y = OB[(c4 * 4 + 1) * OBS + b];
        o.z = OB[(c4 * 4 + 2) * OBS + b];
        o.w = OB[(c4 * 4 + 3) * OBS + b];
        *(float4*)&out[(size_t)(rb + b) * NO + r0 + c4 * 4] = o;
    }
}

// =============== fallback tier 2: single fused kernel, no workspace ===============
#define FT      1024
#define FBPB    64
#define FXS     514
#define FHS     65
#define FOBTS   260
#define FLDS    (99072 + 1544)
__device__ __forceinline__ unsigned short f2bf16s(float f) { return (unsigned short)f2bf_rne(f); }
__device__ __forceinline__ float bf2f(unsigned short h) { return __uint_as_float(((unsigned int)h) << 16); }
__device__ __forceinline__ float edge_act2(float z, int a, float k) {
    float ex = fast_exp2(k * z);
    float rc = fast_rcp(1.f + ex);
    return (a == 2) ? (1.f - 2.f * rc) : ((a == 4) ? rc : ((a == 3) ? fmaxf(z, 0.f) : z));
}
__global__ __launch_bounds__(FT)
void wann_fused(const float* __restrict__ x,
                const int* __restrict__ rows_h, const int* __restrict__ cols_h,
                const int* __restrict__ acts_h, const float* __restrict__ wh,
                const int* __restrict__ rows_o, const int* __restrict__ cols_o,
                const int* __restrict__ acts_o, const float* __restrict__ wo,
                float* __restrict__ out, int Eh, int Eo)
{
    extern __shared__ char lds[];
    unsigned short* X   = (unsigned short*)lds;
    float*          H   = (float*)(lds + 65792);
    float*          OBT = (float*)lds;
    int*            offsH = (int*)(lds + 99072);
    int*            offsO = offsH + (NH + 1);
    const int tid  = threadIdx.x;
    const int lane = tid & 63;
    const int wv   = tid >> 6;
    const int rb   = blockIdx.x * FBPB;
    const int* wh_i = (const int*)wh;
    const int* wo_i = (const int*)wo;
    {
        const float4* xv = (const float4*)(x + (size_t)rb * IN_DIM);
        #pragma unroll
        for (int kk = 0; kk < (FBPB * IN_DIM / 4) / FT; ++kk) {
            int v = tid + kk * FT;
            int r = v >> 7, i = v & 127;
            float4 f = xv[v];
            unsigned int lo = (unsigned int)f2bf16s(f.x) | ((unsigned int)f2bf16s(f.y) << 16);
            unsigned int hi = (unsigned int)f2bf16s(f.z) | ((unsigned int)f2bf16s(f.w) << 16);
            unsigned int* dst = (unsigned int*)&X[r * FXS + i * 4];
            dst[0] = lo; dst[1] = hi;
        }
    }
    if (tid <= NH) offsH[tid] = lower_bound_dev(rows_h, Eh, tid);
    else if (tid <= NH + 1 + NO) offsO[tid - (NH + 1)] = lower_bound_dev(rows_o, Eo, tid - (NH + 1));
    __syncthreads();
    for (int r = wv * (NH / 16); r < (wv + 1) * (NH / 16); ++r) {
        const int e0 = rfl(offsH[r]); const int e1 = rfl(offsH[r + 1]);
        float acc = 0.f;
        #pragma unroll 4
        for (int e = e0; e < e1; ++e) {
            int col = rfl(cols_h[e]); int a = rfl(acts_h[e]);
            float w = __int_as_float(rfl(wh_i[e]));
            acc += edge_act2(bf2f(X[lane * FXS + col]) * w, a, act_k(a));
        }
        H[r * FHS + lane] = acc;
    }
    __syncthreads();
    float res[NO / 16];
    #pragma unroll
    for (int rr = 0; rr < NO / 16; ++rr) {
        const int r = wv * (NO / 16) + rr;
        const int e0 = rfl(offsO[r]); const int e1 = rfl(offsO[r + 1]);
        float acc = 0.f;
        #pragma unroll 4
        for (int e = e0; e < e1; ++e) {
            int col = rfl(cols_o[e]); int a = rfl(acts_o[e]);
            float w = __int_as_float(rfl(wo_i[e]));
            float v = (col < IN_DIM) ? bf2f(X[lane * FXS + col]) : H[(col - IN_DIM) * FHS + lane];
            acc += edge_act2(v * w, a, act_k(a));
        }
        res[rr] = fast_tanh(acc);
    }
    __syncthreads();
    #pragma unroll
    for (int rr = 0; rr < NO / 16; ++rr)
        OBT[lane * FOBTS + wv * (NO / 16) + rr] = res[rr];
    __syncthreads();
    #pragma unroll
    for (int kk = 0; kk < (FBPB * NO / 4) / FT; ++kk) {
        int v = tid + kk * FT;
        int c4 = v & 63, b = v >> 6;
        float4 o = *(const float4*)&OBT[b * FOBTS + c4 * 4];
        *(float4*)&out[(size_t)(rb + b) * NO + c4 * 4] = o;
    }
}

extern "C" void kernel_launch(void* const* d_in, const int* in_sizes, int n_in,
                              void* d_out, int out_size, void* d_ws, size_t ws_size,
                              hipStream_t stream) {
    const float* x      = (const float*)d_in[0];
    const float* wh     = (const float*)d_in[1];
    const float* wo     = (const float*)d_in[2];
    const int*   rows_h = (const int*)d_in[3];
    const int*   cols_h = (const int*)d_in[4];
    const int*   acts_h = (const int*)d_in[5];
    const int*   rows_o = (const int*)d_in[6];
    const int*   cols_o = (const int*)d_in[7];
    const int*   acts_o = (const int*)d_in[8];
    float*       out    = (float*)d_out;

    int Eh = in_sizes[1];
    int Eo = in_sizes[2];

    // ws layout: [offs_h@0][offs_o@1024][packed_h@4096][packed_o][xt bf16][Ht f32]
    char* ws = (char*)d_ws;
    int*  offs_h   = (int*)ws;
    int*  offs_o   = (int*)(ws + 1024);
    int4* packed_h = (int4*)(ws + 4096);
    int4* packed_o = packed_h + Eh;
    size_t tier_packed = 4096 + (size_t)(Eh + Eo) * 16;
    size_t xt_off      = (tier_packed + 255) & ~(size_t)255;
    unsigned short* xt = (unsigned short*)(ws + xt_off);
    size_t ht_off      = (xt_off + (size_t)IN_DIM * BATCH * 2 + 255) & ~(size_t)255;
    float* Ht          = (float*)(ws + ht_off);
    size_t need_full   = ht_off + (size_t)NH * BATCH * 4;

    if (ws_size >= need_full) {
        void* kargs[] = {
            (void*)&x, (void*)&rows_h, (void*)&cols_h, (void*)&acts_h, (void*)&wh,
            (void*)&rows_o, (void*)&cols_o, (void*)&acts_o, (void*)&wo,
            (void*)&out, (void*)&Eh, (void*)&Eo,
            (void*)&xt, (void*)&Ht, (void*)&offs_h, (void*)&offs_o,
            (void*)&packed_h, (void*)&packed_o };
        hipError_t err = hipLaunchCooperativeKernel((const void*)wann_coop,
                                                    dim3(1024), dim3(512),
                                                    kargs, 0, stream);
        if (err != hipSuccess) {
            (void)hipGetLastError();   // clear; fall back to proven 3-kernel path
            const int ntasks      = (NH + 1) + (NO + 1) + Eh + Eo;
            const int edge_blocks = (ntasks + 255) / 256;
            const int tile_blocks = (BATCH / 64) * (IN_DIM / 64);
            prep_fused<<<tile_blocks + edge_blocks, 256, 0, stream>>>(
                x, xt, rows_h, cols_h, acts_h, wh, rows_o, cols_o, acts_o, wo,
                Eh, Eo, tile_blocks, offs_h, offs_o, packed_h, packed_o);
            hidden_kernel<<<1024, 512, 0, stream>>>(xt, offs_h, packed_h, Ht);
            output_kernel<<<1024, 512, 0, stream>>>(xt, Ht, offs_o, packed_o, out);
        }
    } else {
        wann_fused<<<BATCH / FBPB, FT, FLDS, stream>>>(
            x, rows_h, cols_h, acts_h, wh, rows_o, cols_o, acts_o, wo, out, Eh, Eo);
    }
}

// Round 9
// 140.496 us; speedup vs baseline: 2.7964x; 2.7964x over previous
//
#include <hip/hip_runtime.h>
#include <math.h>

// Static graph dims
#define BATCH   16384
#define IN_DIM  512
#define NH      128
#define NO      256
#define L2E     1.4426950408889634f

__device__ __forceinline__ float fast_rcp(float x) { return __builtin_amdgcn_rcpf(x); }
__device__ __forceinline__ float fast_exp2(float x) {
#if __has_builtin(__builtin_amdgcn_exp2f)
    return __builtin_amdgcn_exp2f(x);
#else
    return exp2f(x);
#endif
}
__device__ __forceinline__ int rfl(int v) { return __builtin_amdgcn_readfirstlane(v); }

__device__ __forceinline__ float fast_tanh(float z) {
    float ex = fast_exp2(2.f * L2E * z);
    return 1.f - 2.f * fast_rcp(1.f + ex);
}
__device__ __forceinline__ float fast_sig(float z) {
    float ex = fast_exp2(-L2E * z);
    return fast_rcp(1.f + ex);
}
__device__ __forceinline__ float act_k(int a) {
    return (a == 2) ? (2.f * L2E) : ((a == 4) ? -L2E : 0.f);
}

// act ids: 1=identity, 2=tanh, 3=relu, 4=sigmoid. `a` wave-uniform -> scalar branch;
// identity/relu skip the quarter-rate exp2/rcp entirely.
__device__ __forceinline__ void acc_act4(float4& acc, float4 v, float w, int a) {
    float zx = v.x * w, zy = v.y * w, zz = v.z * w, zw = v.w * w;
    if (a == 2) {
        acc.x += fast_tanh(zx); acc.y += fast_tanh(zy);
        acc.z += fast_tanh(zz); acc.w += fast_tanh(zw);
    } else if (a == 4) {
        acc.x += fast_sig(zx); acc.y += fast_sig(zy);
        acc.z += fast_sig(zz); acc.w += fast_sig(zw);
    } else if (a == 3) {
        acc.x += fmaxf(zx, 0.f); acc.y += fmaxf(zy, 0.f);
        acc.z += fmaxf(zz, 0.f); acc.w += fmaxf(zw, 0.f);
    } else {
        acc.x += zx; acc.y += zy; acc.z += zz; acc.w += zw;
    }
}

__device__ __forceinline__ unsigned int f2bf_rne(float f) {
    unsigned int u = __float_as_uint(f);
    return (u + 0x7FFFu + ((u >> 16) & 1u)) >> 16;
}
__device__ __forceinline__ float bf_lo(unsigned int u) { return __uint_as_float(u << 16); }
__device__ __forceinline__ float bf_hi(unsigned int u) { return __uint_as_float(u & 0xFFFF0000u); }

__device__ __forceinline__ int lower_bound_dev(const int* __restrict__ arr, int n, int v) {
    int lo = 0, hi = n;
    while (lo < hi) { int m = (lo + hi) >> 1; if (arr[m] < v) lo = m + 1; else hi = m; }
    return lo;
}

// ---- shared inner loops ----
__device__ __forceinline__ float4 run_hidden_row(const unsigned short* __restrict__ xt,
                                                 const int4* __restrict__ packed_h,
                                                 int e0, int e1, int bi) {
    float4 acc = make_float4(0.f, 0.f, 0.f, 0.f);
    #pragma unroll 4
    for (int e = e0; e < e1; ++e) {
        int4 p  = packed_h[e];                       // uniform addr -> s_load
        int col = rfl(p.x);
        int a   = rfl(p.y);
        float w = __int_as_float(rfl(p.z));
        uint2 uu = *(const uint2*)(xt + (size_t)col * BATCH + bi);
        float4 v = make_float4(bf_lo(uu.x), bf_hi(uu.x), bf_lo(uu.y), bf_hi(uu.y));
        acc_act4(acc, v, w, a);
    }
    return acc;
}
__device__ __forceinline__ float4 run_output_row(const unsigned short* __restrict__ xt,
                                                 const float* __restrict__ Ht,
                                                 const int4* __restrict__ packed_o,
                                                 int e0, int e1, int bi) {
    float4 acc = make_float4(0.f, 0.f, 0.f, 0.f);
    #pragma unroll 4
    for (int e = e0; e < e1; ++e) {
        int4 p  = packed_o[e];
        int col = rfl(p.x);
        int a   = rfl(p.y);
        float w = __int_as_float(rfl(p.z));
        float4 v;
        if (col < IN_DIM) {                           // wave-uniform branch
            uint2 uu = *(const uint2*)(xt + (size_t)col * BATCH + bi);
            v = make_float4(bf_lo(uu.x), bf_hi(uu.x), bf_lo(uu.y), bf_hi(uu.y));
        } else {
            v = *(const float4*)&Ht[(size_t)(col - IN_DIM) * BATCH + bi];
        }
        acc_act4(acc, v, w, a);
    }
    return acc;
}

// XCD-coherent slice decode (1024-block grids): s in 0..63, rg in 0..15
__device__ __forceinline__ void decode_slice(int bid, int& s, int& rg) {
    int xcd = bid & 7;
    int m   = bid >> 3;
    rg      = m & 15;
    int u   = m >> 4;
    s = ((u >> 1) << 4) | (xcd << 1) | (u & 1);
}

// ---------------- prep: x -> bf16 xt[IN][B] via 128x128 tiles + CSR + packed ----------------
// 512 tile blocks (2/CU), 66KB dynamic LDS, uint4 (16B) xt stores in 256B/column chunks.
__global__ __launch_bounds__(256)
void prep_fused(const float* __restrict__ x, unsigned short* __restrict__ xt,
                const int* __restrict__ rows_h, const int* __restrict__ cols_h,
                const int* __restrict__ acts_h, const float* __restrict__ wh,
                const int* __restrict__ rows_o, const int* __restrict__ cols_o,
                const int* __restrict__ acts_o, const float* __restrict__ wo,
                int Eh, int Eo, int tile_blocks,
                int* __restrict__ offs_h, int* __restrict__ offs_o,
                int4* __restrict__ packed_h, int4* __restrict__ packed_o) {
    extern __shared__ float tile[];          // [128][129] = 66048 B
    if ((int)blockIdx.x < tile_blocks) {
        const int bt = blockIdx.x & (BATCH / 128 - 1);   // 128 batch tiles
        const int ct = blockIdx.x >> 7;                  // 4 col tiles
        const int b0 = bt * 128, c0 = ct * 128;
        // load: 128 rows x 32 float4 (512B/row, coalesced)
        #pragma unroll
        for (int it = 0; it < 16; ++it) {
            int v = threadIdx.x + it * 256;
            int b = v >> 5, i = v & 31;
            float4 f = *(const float4*)&x[(size_t)(b0 + b) * IN_DIM + c0 + i * 4];
            float* d = &tile[b * 129 + i * 4];
            d[0] = f.x; d[1] = f.y; d[2] = f.z; d[3] = f.w;
        }
        __syncthreads();
        // writeout: per col 128 batches -> 16 uint4; per wave 4 cols x 256B contiguous
        #pragma unroll
        for (int it = 0; it < 8; ++it) {
            int v = threadIdx.x + it * 256;
            int c = v >> 4, j = v & 15;
            int b = j * 8;
            unsigned int uu[4];
            #pragma unroll
            for (int q = 0; q < 4; ++q) {
                float lo = tile[(b + 2 * q)     * 129 + c];
                float hi = tile[(b + 2 * q + 1) * 129 + c];
                uu[q] = f2bf_rne(lo) | (f2bf_rne(hi) << 16);
            }
            *(uint4*)&xt[(size_t)(c0 + c) * BATCH + b0 + b] = make_uint4(uu[0], uu[1], uu[2], uu[3]);
        }
        return;
    }
    int t = (blockIdx.x - tile_blocks) * 256 + threadIdx.x;
    if (t <= NH) offs_h[t] = lower_bound_dev(rows_h, Eh, t);
    else if (t <= NH + 1 + NO) offs_o[t - (NH + 1)] = lower_bound_dev(rows_o, Eo, t - (NH + 1));
    int u = t - (NH + 1 + NO + 1);
    if (u >= 0 && u < Eh) {
        int a = acts_h[u];
        packed_h[u] = make_int4(cols_h[u], a, __float_as_int(wh[u]), 0);
    }
    u -= Eh;
    if (u >= 0 && u < Eo) {
        int a = acts_o[u];
        packed_o[u] = make_int4(cols_o[u], a, __float_as_int(wo[u]), 0);
    }
}

// ---------------- hidden: wave = 1 row x 256-batch (4/lane); 1024x512 -> 8 waves/SIMD ----------------
__global__ __launch_bounds__(512)
void hidden_kernel(const unsigned short* __restrict__ xt, const int* __restrict__ offs_h,
                   const int4* __restrict__ packed_h, float* __restrict__ Ht) {
    const int lane = threadIdx.x & 63;
    const int wv   = threadIdx.x >> 6;
    int s, rg;
    decode_slice(blockIdx.x, s, rg);
    const int bi = s * 256 + lane * 4;
    const int r  = rg * 8 + wv;
    const int e0 = rfl(offs_h[r]);
    const int e1 = rfl(offs_h[r + 1]);
    float4 acc = run_hidden_row(xt, packed_h, e0, e1, bi);
    *(float4*)&Ht[(size_t)r * BATCH + bi] = acc;
}

// ---------------- output: wave = 2 rows x 256-batch (4/lane); OB transpose in LDS ----------------
#define OBS 260
__global__ __launch_bounds__(512)
void output_kernel(const unsigned short* __restrict__ xt, const float* __restrict__ Ht,
                   const int* __restrict__ offs_o, const int4* __restrict__ packed_o,
                   float* __restrict__ out) {
    __shared__ float OB[16 * OBS];
    const int lane = threadIdx.x & 63;
    const int wv   = threadIdx.x >> 6;
    int s, rg;
    decode_slice(blockIdx.x, s, rg);
    const int rb = s * 256;
    const int r0 = rg * 16;
    const int bi = rb + lane * 4;
    #pragma unroll
    for (int rr = wv * 2; rr < wv * 2 + 2; ++rr) {
        const int r  = r0 + rr;
        const int e0 = rfl(offs_o[r]);
        const int e1 = rfl(offs_o[r + 1]);
        float4 acc = run_output_row(xt, Ht, packed_o, e0, e1, bi);
        OB[rr * OBS + lane * 4 + 0] = fast_tanh(acc.x);
        OB[rr * OBS + lane * 4 + 1] = fast_tanh(acc.y);
        OB[rr * OBS + lane * 4 + 2] = fast_tanh(acc.z);
        OB[rr * OBS + lane * 4 + 3] = fast_tanh(acc.w);
    }
    __syncthreads();
    // out[rb+b][r0 + c4*4 ..]: 4 lanes cover one b's 64B chunk; OB reads <=2-way
    #pragma unroll
    for (int it = 0; it < 2; ++it) {
        int v  = threadIdx.x + it * 512;
        int c4 = v & 3;
        int b  = v >> 2;
        float4 o;
        o.x = OB[(c4 * 4 + 0) * OBS + b];
        o.y = OB[(c4 * 4 + 1) * OBS + b];
        o.z = OB[(c4 * 4 + 2) * OBS + b];
        o.w = OB[(c4 * 4 + 3) * OBS + b];
        *(float4*)&out[(size_t)(rb + b) * NO + r0 + c4 * 4] = o;
    }
}

// =============== fallback: single fused kernel, no workspace ===============
#define FT      1024
#define FBPB    64
#define FXS     514
#define FHS     65
#define FOBTS   260
#define FLDS    (99072 + 1544)
__device__ __forceinline__ unsigned short f2bf16s(float f) { return (unsigned short)f2bf_rne(f); }
__device__ __forceinline__ float bf2f(unsigned short h) { return __uint_as_float(((unsigned int)h) << 16); }
__device__ __forceinline__ float edge_act2(float z, int a, float k) {
    float ex = fast_exp2(k * z);
    float rc = fast_rcp(1.f + ex);
    return (a == 2) ? (1.f - 2.f * rc) : ((a == 4) ? rc : ((a == 3) ? fmaxf(z, 0.f) : z));
}
__global__ __launch_bounds__(FT)
void wann_fused(const float* __restrict__ x,
                const int* __restrict__ rows_h, const int* __restrict__ cols_h,
                const int* __restrict__ acts_h, const float* __restrict__ wh,
                const int* __restrict__ rows_o, const int* __restrict__ cols_o,
                const int* __restrict__ acts_o, const float* __restrict__ wo,
                float* __restrict__ out, int Eh, int Eo)
{
    extern __shared__ char lds[];
    unsigned short* X   = (unsigned short*)lds;
    float*          H   = (float*)(lds + 65792);
    float*          OBT = (float*)lds;
    int*            offsH = (int*)(lds + 99072);
    int*            offsO = offsH + (NH + 1);
    const int tid  = threadIdx.x;
    const int lane = tid & 63;
    const int wv   = tid >> 6;
    const int rb   = blockIdx.x * FBPB;
    const int* wh_i = (const int*)wh;
    const int* wo_i = (const int*)wo;
    {
        const float4* xv = (const float4*)(x + (size_t)rb * IN_DIM);
        #pragma unroll
        for (int kk = 0; kk < (FBPB * IN_DIM / 4) / FT; ++kk) {
            int v = tid + kk * FT;
            int r = v >> 7, i = v & 127;
            float4 f = xv[v];
            unsigned int lo = (unsigned int)f2bf16s(f.x) | ((unsigned int)f2bf16s(f.y) << 16);
            unsigned int hi = (unsigned int)f2bf16s(f.z) | ((unsigned int)f2bf16s(f.w) << 16);
            unsigned int* dst = (unsigned int*)&X[r * FXS + i * 4];
            dst[0] = lo; dst[1] = hi;
        }
    }
    if (tid <= NH) offsH[tid] = lower_bound_dev(rows_h, Eh, tid);
    else if (tid <= NH + 1 + NO) offsO[tid - (NH + 1)] = lower_bound_dev(rows_o, Eo, tid - (NH + 1));
    __syncthreads();
    for (int r = wv * (NH / 16); r < (wv + 1) * (NH / 16); ++r) {
        const int e0 = rfl(offsH[r]); const int e1 = rfl(offsH[r + 1]);
        float acc = 0.f;
        #pragma unroll 4
        for (int e = e0; e < e1; ++e) {
            int col = rfl(cols_h[e]); int a = rfl(acts_h[e]);
            float w = __int_as_float(rfl(wh_i[e]));
            acc += edge_act2(bf2f(X[lane * FXS + col]) * w, a, act_k(a));
        }
        H[r * FHS + lane] = acc;
    }
    __syncthreads();
    float res[NO / 16];
    #pragma unroll
    for (int rr = 0; rr < NO / 16; ++rr) {
        const int r = wv * (NO / 16) + rr;
        const int e0 = rfl(offsO[r]); const int e1 = rfl(offsO[r + 1]);
        float acc = 0.f;
        #pragma unroll 4
        for (int e = e0; e < e1; ++e) {
            int col = rfl(cols_o[e]); int a = rfl(acts_o[e]);
            float w = __int_as_float(rfl(wo_i[e]));
            float v = (col < IN_DIM) ? bf2f(X[lane * FXS + col]) : H[(col - IN_DIM) * FHS + lane];
            acc += edge_act2(v * w, a, act_k(a));
        }
        res[rr] = fast_tanh(acc);
    }
    __syncthreads();
    #pragma unroll
    for (int rr = 0; rr < NO / 16; ++rr)
        OBT[lane * FOBTS + wv * (NO / 16) + rr] = res[rr];
    __syncthreads();
    #pragma unroll
    for (int kk = 0; kk < (FBPB * NO / 4) / FT; ++kk) {
        int v = tid + kk * FT;
        int c4 = v & 63, b = v >> 6;
        float4 o = *(const float4*)&OBT[b * FOBTS + c4 * 4];
        *(float4*)&out[(size_t)(rb + b) * NO + c4 * 4] = o;
    }
}

extern "C" void kernel_launch(void* const* d_in, const int* in_sizes, int n_in,
                              void* d_out, int out_size, void* d_ws, size_t ws_size,
                              hipStream_t stream) {
    const float* x      = (const float*)d_in[0];
    const float* wh     = (const float*)d_in[1];
    const float* wo     = (const float*)d_in[2];
    const int*   rows_h = (const int*)d_in[3];
    const int*   cols_h = (const int*)d_in[4];
    const int*   acts_h = (const int*)d_in[5];
    const int*   rows_o = (const int*)d_in[6];
    const int*   cols_o = (const int*)d_in[7];
    const int*   acts_o = (const int*)d_in[8];
    float*       out    = (float*)d_out;

    const int Eh = in_sizes[1];
    const int Eo = in_sizes[2];

    // ws layout: [offs_h@0][offs_o@1024][packed_h@4096][packed_o][xt bf16][Ht f32]
    char* ws = (char*)d_ws;
    int*  offs_h   = (int*)ws;
    int*  offs_o   = (int*)(ws + 1024);
    int4* packed_h = (int4*)(ws + 4096);
    int4* packed_o = packed_h + Eh;
    size_t tier_packed = 4096 + (size_t)(Eh + Eo) * 16;
    size_t xt_off      = (tier_packed + 255) & ~(size_t)255;
    unsigned short* xt = (unsigned short*)(ws + xt_off);
    size_t ht_off      = (xt_off + (size_t)IN_DIM * BATCH * 2 + 255) & ~(size_t)255;
    float* Ht          = (float*)(ws + ht_off);
    size_t need_full   = ht_off + (size_t)NH * BATCH * 4;

    if (ws_size >= need_full) {
        const int ntasks      = (NH + 1) + (NO + 1) + Eh + Eo;
        const int edge_blocks = (ntasks + 255) / 256;
        const int tile_blocks = (BATCH / 128) * (IN_DIM / 128);   // 512
        prep_fused<<<tile_blocks + edge_blocks, 256, 128 * 129 * 4, stream>>>(
            x, xt, rows_h, cols_h, acts_h, wh, rows_o, cols_o, acts_o, wo,
            Eh, Eo, tile_blocks, offs_h, offs_o, packed_h, packed_o);
        hidden_kernel<<<1024, 512, 0, stream>>>(xt, offs_h, packed_h, Ht);
        output_kernel<<<1024, 512, 0, stream>>>(xt, Ht, offs_o, packed_o, out);
    } else {
        wann_fused<<<BATCH / FBPB, FT, FLDS, stream>>>(
            x, rows_h, cols_h, acts_h, wh, rows_o, cols_o, acts_o, wo, out, Eh, Eo);
    }
}